// Round 3
// baseline (242.712 us; speedup 1.0000x reference)
//
#include <hip/hip_runtime.h>
#include <math.h>

// Problem constants (fixed by the reference).
#define BB    4
#define CC    256
#define CHN   128
#define NN    4096

typedef short short8 __attribute__((ext_vector_type(8)));   // 8 bf16 (MFMA A/B frag)
typedef float f32x4  __attribute__((ext_vector_type(4)));   // MFMA C/D frag
typedef unsigned short u16;
typedef u16  us4 __attribute__((ext_vector_type(4)));

#define MFMA16(a, b, c) __builtin_amdgcn_mfma_f32_16x16x32_bf16((a), (b), (c), 0, 0, 0)

static __device__ __forceinline__ u16 f2bf(float f) {           // RNE float->bf16
    union { float f; unsigned u; } v; v.f = f;
    unsigned r = v.u + 0x7FFFu + ((v.u >> 16) & 1u);
    return (u16)(r >> 16);
}
// XOR-swizzled LDS address (u16 units) for [row][128] bf16 tiles, 16B chunks.
static __device__ __forceinline__ int sw128(int row, int u) {
    return row * 128 + ((u ^ (row & 7)) << 3);
}

// ---------------------------------------------------------------------------
// K0: convert the 4 weight matrices fp32->bf16. wall = [tw|pw|gw|Ww], each
// 32768 elems (128x256 or 256x128), all k-major for their MFMA use.
// ---------------------------------------------------------------------------
__global__ __launch_bounds__(256) void k_cvtw(
    const float* __restrict__ tw, const float* __restrict__ pw,
    const float* __restrict__ gw, const float* __restrict__ Ww,
    u16* __restrict__ wall)
{
    int idx = (blockIdx.x * 256 + threadIdx.x) * 4;   // 0 .. 131071
    const float* s = (idx < 32768) ? tw
                   : (idx < 65536) ? pw
                   : (idx < 98304) ? gw : Ww;
    float4 v = *(const float4*)(s + (idx & 32767));
    us4 r = { f2bf(v.x), f2bf(v.y), f2bf(v.z), f2bf(v.w) };
    *(us4*)(wall + idx) = r;
}

// ---------------------------------------------------------------------------
// K1: MFMA projections, 512 threads. A = weights (global k-major frags),
// B = x^T tile in LDS (staged once, frags hoisted to regs, reused 3x).
//  tht/pht: [b][n][c] bf16 (k-major for downstream A-frags)
//  gg:      [b][c][n] bf16 (k-major in j for the attention PV A-frags)
// Grid (64, B). Waves: 2(o-half) x 4(n-group of 16).
// ---------------------------------------------------------------------------
__global__ __launch_bounds__(512) void k_proj(
    const float* __restrict__ x, const u16* __restrict__ wall,
    const float* __restrict__ tb, const float* __restrict__ pb,
    const float* __restrict__ gbias,
    u16* __restrict__ tht, u16* __restrict__ pht, u16* __restrict__ gg)
{
    __shared__ u16 xs[64 * 264];    // x^T tile [n][c], pitch 264
    __shared__ u16 gbuf[128 * 68];  // g transpose bounce [o][n]
    const int tid = threadIdx.x;
    const int n0  = blockIdx.x * 64;
    const int b   = blockIdx.y;
    const int ln  = tid & 15, q = (tid >> 4) & 3, wid = tid >> 6;
    const int ow  = wid & 1, nw = wid >> 1;

    // stage x^T (fp32 -> bf16 transposed scatter)
    for (int p = 0; p < 8; ++p) {
        int id = p * 512 + tid;          // 4096 chunks: c(256) x n4(16)
        int c = id >> 4, n4 = (id & 15) * 4;
        float4 xv = *(const float4*)(x + ((size_t)b * CC + c) * NN + n0 + n4);
        xs[(n4 + 0) * 264 + c] = f2bf(xv.x);
        xs[(n4 + 1) * 264 + c] = f2bf(xv.y);
        xs[(n4 + 2) * 264 + c] = f2bf(xv.z);
        xs[(n4 + 3) * 264 + c] = f2bf(xv.w);
    }
    __syncthreads();

    // hoist this wave's B-frags (row n = nw*16+ln, all K=256)
    short8 bfr[8];
    #pragma unroll
    for (int ks = 0; ks < 8; ++ks)
        bfr[ks] = *(const short8*)(&xs[(nw * 16 + ln) * 264 + ks * 32 + q * 8]);

    for (int pr = 0; pr < 3; ++pr) {
        const u16* wsrc = wall + pr * 32768;
        f32x4 acc[4];
        #pragma unroll
        for (int oo = 0; oo < 4; ++oo) acc[oo] = (f32x4){0.f, 0.f, 0.f, 0.f};
        for (int ks = 0; ks < 8; ++ks) {
            short8 a[4];
            #pragma unroll
            for (int oo = 0; oo < 4; ++oo)
                a[oo] = *(const short8*)(wsrc + (size_t)(ow*64 + oo*16 + ln) * 256 + ks*32 + q*8);
            #pragma unroll
            for (int oo = 0; oo < 4; ++oo)
                acc[oo] = MFMA16(a[oo], bfr[ks], acc[oo]);
        }
        const float* bias = (pr == 0) ? tb : (pr == 1 ? pb : gbias);
        if (pr < 2) {
            // D: col=n (lane), rows = 4 consecutive o -> us4 along c in [n][c]
            u16* dst = (pr == 0) ? tht : pht;
            const int n = n0 + nw * 16 + ln;
            #pragma unroll
            for (int oo = 0; oo < 4; ++oo) {
                int o = ow * 64 + oo * 16 + q * 4;
                float4 bv = *(const float4*)(bias + o);
                f32x4 v = acc[oo];
                us4 r = { f2bf(v.x + bv.x), f2bf(v.y + bv.y),
                          f2bf(v.z + bv.z), f2bf(v.w + bv.w) };
                *(us4*)(dst + ((size_t)b * NN + n) * CHN + o) = r;
            }
        } else {
            const int nl = nw * 16 + ln;
            #pragma unroll
            for (int oo = 0; oo < 4; ++oo) {
                int o = ow * 64 + oo * 16 + q * 4;
                float4 bv = *(const float4*)(bias + o);
                f32x4 v = acc[oo];
                gbuf[(o + 0) * 68 + nl] = f2bf(v.x + bv.x);
                gbuf[(o + 1) * 68 + nl] = f2bf(v.y + bv.y);
                gbuf[(o + 2) * 68 + nl] = f2bf(v.z + bv.z);
                gbuf[(o + 3) * 68 + nl] = f2bf(v.w + bv.w);
            }
            __syncthreads();
            for (int p = 0; p < 4; ++p) {
                int id = p * 512 + tid;      // 2048 chunks: c(128) x n4(16)
                int c = id >> 4, n4 = (id & 15) * 4;
                us4 r = *(const us4*)(&gbuf[c * 68 + n4]);
                *(us4*)(gg + ((size_t)b * CHN + c) * NN + n0 + n4) = r;
            }
        }
    }
}

// ---------------------------------------------------------------------------
// K2: Lbuf[b][j] = ln( sum_i exp(theta_j . phi_i) ).  512 threads.
// Block: j-tile 64 resident (A-frags direct from global tht), i-loop 16x256
// staged in LDS. Waves: 2(j-half of 32) x 4(i-group of 64).
// No max-subtraction needed: |S| <= ~66 << 88.
// ---------------------------------------------------------------------------
__global__ __launch_bounds__(512) void k_rowsum(
    const u16* __restrict__ tht, const u16* __restrict__ pht,
    float* __restrict__ Lbuf)
{
    __shared__ u16 ph_s[256 * 128];
    __shared__ float zs[64][4];
    const int tid = threadIdx.x;
    const int j0  = blockIdx.x * 64;
    const int b   = blockIdx.y;
    const int ln  = tid & 15, q = (tid >> 4) & 3, wid = tid >> 6;
    const int jw  = wid & 1, iw = wid >> 1;
    const u16* thb = tht + (size_t)b * NN * CHN;
    const u16* phb = pht + (size_t)b * NN * CHN;

    float zp[2][4];
    #pragma unroll
    for (int jj = 0; jj < 2; ++jj)
        #pragma unroll
        for (int r = 0; r < 4; ++r) zp[jj][r] = 0.f;

    for (int is = 0; is < 16; ++is) {
        for (int p = 0; p < 8; ++p) {
            int id = p * 512 + tid;
            int row = id >> 4, u = id & 15;
            short8 v = *(const short8*)(phb + (size_t)(is * 256 + row) * 128 + u * 8);
            *(short8*)(&ph_s[sw128(row, u)]) = v;
        }
        __syncthreads();

        f32x4 s[2][4];
        #pragma unroll
        for (int jj = 0; jj < 2; ++jj)
            #pragma unroll
            for (int ii = 0; ii < 4; ++ii) s[jj][ii] = (f32x4){0.f, 0.f, 0.f, 0.f};
        for (int ks = 0; ks < 4; ++ks) {
            short8 a[2], bb[4];
            #pragma unroll
            for (int jj = 0; jj < 2; ++jj)
                a[jj] = *(const short8*)(thb + (size_t)(j0 + jw*32 + jj*16 + ln) * 128 + ks*32 + q*8);
            #pragma unroll
            for (int ii = 0; ii < 4; ++ii)
                bb[ii] = *(const short8*)(&ph_s[sw128(iw*64 + ii*16 + ln, ks*4 + q)]);
            #pragma unroll
            for (int jj = 0; jj < 2; ++jj)
                #pragma unroll
                for (int ii = 0; ii < 4; ++ii)
                    s[jj][ii] = MFMA16(a[jj], bb[ii], s[jj][ii]);
        }
        #pragma unroll
        for (int jj = 0; jj < 2; ++jj)
            #pragma unroll
            for (int ii = 0; ii < 4; ++ii) {
                f32x4 v = s[jj][ii];
                zp[jj][0] += __expf(v.x);
                zp[jj][1] += __expf(v.y);
                zp[jj][2] += __expf(v.z);
                zp[jj][3] += __expf(v.w);
            }
        __syncthreads();
    }

    #pragma unroll
    for (int jj = 0; jj < 2; ++jj)
        #pragma unroll
        for (int r = 0; r < 4; ++r) {
            float v = zp[jj][r];
            v += __shfl_xor(v, 1);
            v += __shfl_xor(v, 2);
            v += __shfl_xor(v, 4);
            v += __shfl_xor(v, 8);
            if (ln == 0) zs[jw*32 + jj*16 + q*4 + r][iw] = v;
        }
    __syncthreads();
    if (tid < 64)
        Lbuf[(size_t)b * NN + j0 + tid] =
            __logf(zs[tid][0] + zs[tid][1] + zs[tid][2] + zs[tid][3]);
}

// ---------------------------------------------------------------------------
// K3: fused attention, 512 threads, i-tile 256, j-quarter 1024 (8 steps x128).
//  phase1: S = th_j.ph_i via MFMA with acc INIT = -L_j  -> E = exp(S-L) bf16
//  phase2: innerT[i][c] += E[i][j] * g[c][j]  (A=g global frags, B=E LDS)
// LDS: ph_s 64KB (resident) + E_s 64KB = 128KB -> 8 waves/CU, 2/SIMD.
// th/g A-fragments load straight from global (k-major, L1/L2-hot).
// Grid (16, 4, B) = 256 blocks.
// ---------------------------------------------------------------------------
__global__ __launch_bounds__(512, 2) void k_attn(
    const u16* __restrict__ tht, const u16* __restrict__ pht,
    const u16* __restrict__ gg, const float* __restrict__ Lbuf,
    u16* __restrict__ innerT)
{
    __shared__ u16 ph_s[256 * 128];
    __shared__ u16 E_s [256 * 128];
    const int tid = threadIdx.x;
    const int i0  = blockIdx.x * 256;
    const int jq  = blockIdx.y;
    const int b   = blockIdx.z;
    const int ln  = tid & 15, q = (tid >> 4) & 3, wid = tid >> 6;
    const int g1  = wid & 1;    // phase1: j-half (64); phase2: c-half (64)
    const int g2  = wid >> 1;   // i-group (64), both phases

    const u16*  thb = tht + (size_t)b * NN * CHN;
    const u16*  ggb = gg  + (size_t)b * CHN * NN;
    const float* Lb = Lbuf + (size_t)b * NN;

    { // resident phi i-tile
        const u16* src = pht + ((size_t)b * NN + i0) * CHN;
        for (int p = 0; p < 8; ++p) {
            int id = p * 512 + tid;
            int row = id >> 4, u = id & 15;
            short8 v = *(const short8*)(src + row * 128 + u * 8);
            *(short8*)(&ph_s[sw128(row, u)]) = v;
        }
    }

    f32x4 pacc[4][4];
    #pragma unroll
    for (int cc = 0; cc < 4; ++cc)
        #pragma unroll
        for (int ii = 0; ii < 4; ++ii) pacc[cc][ii] = (f32x4){0.f, 0.f, 0.f, 0.f};

    for (int js = 0; js < 8; ++js) {
        const int j0 = jq * 1024 + js * 128;
        __syncthreads();   // prev phase2 done with E_s (and ph_s staged, js=0)

        // ---- phase 1: S - L (C initialized to -L_j)
        f32x4 s[4][4];
        #pragma unroll
        for (int jj = 0; jj < 4; ++jj) {
            float4 Lv = *(const float4*)(Lb + j0 + g1*64 + jj*16 + q*4);
            f32x4 init = { -Lv.x, -Lv.y, -Lv.z, -Lv.w };
            #pragma unroll
            for (int ii = 0; ii < 4; ++ii) s[jj][ii] = init;
        }
        for (int ks = 0; ks < 4; ++ks) {
            short8 a[4], bb[4];
            #pragma unroll
            for (int jj = 0; jj < 4; ++jj)
                a[jj] = *(const short8*)(thb + (size_t)(j0 + g1*64 + jj*16 + ln) * 128 + ks*32 + q*8);
            #pragma unroll
            for (int ii = 0; ii < 4; ++ii)
                bb[ii] = *(const short8*)(&ph_s[sw128(g2*64 + ii*16 + ln, ks*4 + q)]);
            #pragma unroll
            for (int jj = 0; jj < 4; ++jj)
                #pragma unroll
                for (int ii = 0; ii < 4; ++ii)
                    s[jj][ii] = MFMA16(a[jj], bb[ii], s[jj][ii]);
        }
        // E = exp(S-L) -> E_s[i][j] bf16 (lane: 4 consecutive j at fixed i)
        #pragma unroll
        for (int jj = 0; jj < 4; ++jj) {
            int jl = g1*64 + jj*16 + q*4;
            int u = jl >> 3, off = jl & 7;
            #pragma unroll
            for (int ii = 0; ii < 4; ++ii) {
                int ri = g2*64 + ii*16 + ln;
                f32x4 v = s[jj][ii];
                us4 e = { f2bf(__expf(v.x)), f2bf(__expf(v.y)),
                          f2bf(__expf(v.z)), f2bf(__expf(v.w)) };
                *(us4*)(&E_s[ri*128 + ((u ^ (ri & 7)) << 3) + off]) = e;
            }
        }
        __syncthreads();

        // ---- phase 2: innerT += E * g   (M=c from global g, N=i from E_s)
        for (int ks = 0; ks < 4; ++ks) {
            short8 a[4], bb[4];
            #pragma unroll
            for (int cc = 0; cc < 4; ++cc)
                a[cc] = *(const short8*)(ggb + (size_t)(g1*64 + cc*16 + ln) * NN + j0 + ks*32 + q*8);
            #pragma unroll
            for (int ii = 0; ii < 4; ++ii)
                bb[ii] = *(const short8*)(&E_s[sw128(g2*64 + ii*16 + ln, ks*4 + q)]);
            #pragma unroll
            for (int cc = 0; cc < 4; ++cc)
                #pragma unroll
                for (int ii = 0; ii < 4; ++ii)
                    pacc[cc][ii] = MFMA16(a[cc], bb[ii], pacc[cc][ii]);
        }
    }

    // epilogue: D col=i (lane), rows = 4 consecutive c -> us4 into [i][c]
    u16* dst = innerT + ((size_t)jq * BB + b) * (size_t)NN * CHN;
    #pragma unroll
    for (int cc = 0; cc < 4; ++cc)
        #pragma unroll
        for (int ii = 0; ii < 4; ++ii) {
            int i = i0 + g2*64 + ii*16 + ln;
            int c = g1*64 + cc*16 + q*4;
            f32x4 v = pacc[cc][ii];
            us4 r = { f2bf(v.x), f2bf(v.y), f2bf(v.z), f2bf(v.w) };
            *(us4*)(dst + (size_t)i * CHN + c) = r;
        }
}

// ---------------------------------------------------------------------------
// K4: out[b][o][n] = Wb[o] + x[b][o][n] + sum_c Ww[o][c]*(sum_q innerT_q)[n][c]
// Pure-MFMA, no LDS: A = innerT (k-major in c), B = Ww (k-major in c).
// Quarter partials summed inside the fp32 accumulator (4x K=128 passes).
// Waves: 8 o-groups of 32. Grid (64, B).
// ---------------------------------------------------------------------------
__global__ __launch_bounds__(512) void k_final(
    const u16* __restrict__ innerT, const float* __restrict__ x,
    const u16* __restrict__ Wwbf, const float* __restrict__ Wb,
    float* __restrict__ out)
{
    const int tid = threadIdx.x;
    const int n0  = blockIdx.x * 64;
    const int b   = blockIdx.y;
    const int ln  = tid & 15, q = (tid >> 4) & 3, wid = tid >> 6;

    f32x4 acc[4][2];
    #pragma unroll
    for (int nn = 0; nn < 4; ++nn)
        #pragma unroll
        for (int oo = 0; oo < 2; ++oo) acc[nn][oo] = (f32x4){0.f, 0.f, 0.f, 0.f};

    for (int jq = 0; jq < 4; ++jq) {
        const u16* src = innerT + ((size_t)jq * BB + b) * (size_t)NN * CHN;
        for (int ks = 0; ks < 4; ++ks) {
            short8 a[4], bw[2];
            #pragma unroll
            for (int nn = 0; nn < 4; ++nn)
                a[nn] = *(const short8*)(src + (size_t)(n0 + nn*16 + ln) * CHN + ks*32 + q*8);
            #pragma unroll
            for (int oo = 0; oo < 2; ++oo)
                bw[oo] = *(const short8*)(Wwbf + (size_t)(wid*32 + oo*16 + ln) * CHN + ks*32 + q*8);
            #pragma unroll
            for (int nn = 0; nn < 4; ++nn)
                #pragma unroll
                for (int oo = 0; oo < 2; ++oo)
                    acc[nn][oo] = MFMA16(a[nn], bw[oo], acc[nn][oo]);
        }
    }
    // D: col=o (lane), rows = 4 consecutive n -> float4 along n, fused bias+x
    #pragma unroll
    for (int nn = 0; nn < 4; ++nn)
        #pragma unroll
        for (int oo = 0; oo < 2; ++oo) {
            int o = wid*32 + oo*16 + ln;
            int n = n0 + nn*16 + q*4;
            size_t idx = ((size_t)b * CC + o) * NN + n;
            float4 xv = *(const float4*)(x + idx);
            float wb = Wb[o];
            f32x4 v = acc[nn][oo];
            f32x4 r = { v.x + wb + xv.x, v.y + wb + xv.y,
                        v.z + wb + xv.z, v.w + wb + xv.w };
            *(f32x4*)(out + idx) = r;
        }
}

// ---------------------------------------------------------------------------
extern "C" void kernel_launch(void* const* d_in, const int* in_sizes, int n_in,
                              void* d_out, int out_size, void* d_ws, size_t ws_size,
                              hipStream_t stream)
{
    const float* x  = (const float*)d_in[0];
    const float* tw = (const float*)d_in[1];
    const float* tb = (const float*)d_in[2];
    const float* pw = (const float*)d_in[3];
    const float* pb = (const float*)d_in[4];
    const float* gw = (const float*)d_in[5];
    const float* gb = (const float*)d_in[6];
    const float* Ww = (const float*)d_in[7];
    const float* Wb = (const float*)d_in[8];
    float* out = (float*)d_out;

    // Workspace (~28.3 MB): tht|pht|gg (4MB ea, bf16) | wall (256KB) |
    // Lbuf (64KB fp32) | innerT 4 quarters x 4MB bf16.
    char* p = (char*)d_ws;
    const size_t proj_u16 = (size_t)BB * NN * CHN;   // 2,097,152
    u16*   tht    = (u16*)p;   p += proj_u16 * 2;
    u16*   pht    = (u16*)p;   p += proj_u16 * 2;
    u16*   gg     = (u16*)p;   p += proj_u16 * 2;
    u16*   wall   = (u16*)p;   p += (size_t)131072 * 2;
    float* Lbuf   = (float*)p; p += (size_t)BB * NN * 4;
    u16*   innerT = (u16*)p;

    k_cvtw  <<<128, 256, 0, stream>>>(tw, pw, gw, Ww, wall);
    k_proj  <<<dim3(64, BB), 512, 0, stream>>>(x, wall, tb, pb, gb, tht, pht, gg);
    k_rowsum<<<dim3(64, BB), 512, 0, stream>>>(tht, pht, Lbuf);
    k_attn  <<<dim3(16, 4, BB), 512, 0, stream>>>(tht, pht, gg, Lbuf, innerT);
    k_final <<<dim3(64, BB), 512, 0, stream>>>(innerT, x, wall + 98304, Wb, out);
}

// Round 4
// 205.336 us; speedup vs baseline: 1.1820x; 1.1820x over previous
//
#include <hip/hip_runtime.h>
#include <hip/hip_bf16.h>
#include <math.h>

// Problem constants (fixed by the reference).
#define BB    4
#define CC    256
#define CHN   128
#define NN    4096

typedef short short8 __attribute__((ext_vector_type(8)));   // 8 bf16 (MFMA A/B frag)
typedef float f32x4  __attribute__((ext_vector_type(4)));   // MFMA C/D frag
typedef unsigned short u16;
typedef u16  us4 __attribute__((ext_vector_type(4)));

#define MFMA16(a, b, c) __builtin_amdgcn_mfma_f32_16x16x32_bf16((a), (b), (c), 0, 0, 0)
#define LOG2E 1.4426950408889634f

#if __has_builtin(__builtin_amdgcn_exp2f)
#define EXP2F(x) __builtin_amdgcn_exp2f(x)
#else
#define EXP2F(x) exp2f(x)
#endif
#if __has_builtin(__builtin_amdgcn_logf)
#define LOG2F(x) __builtin_amdgcn_logf(x)   // v_log_f32 IS log2
#else
#define LOG2F(x) log2f(x)
#endif

static __device__ __forceinline__ u16 f2bf(float f) {           // RNE float->bf16
    union { float f; unsigned u; } v; v.f = f;
    unsigned r = v.u + 0x7FFFu + ((v.u >> 16) & 1u);
    return (u16)(r >> 16);
}
// packed f32x2 -> bf16x2 (v_cvt_pk_bf16_f32 on gfx950 via hip_bf16.h)
static __device__ __forceinline__ unsigned pkbf(float a, float b) {
    __hip_bfloat162 h = __float22bfloat162_rn(make_float2(a, b));
    return *reinterpret_cast<unsigned*>(&h);
}
// XOR-swizzled LDS address (u16 units) for [row][128] bf16 tiles, 16B chunks.
static __device__ __forceinline__ int sw128(int row, int u) {
    return row * 128 + ((u ^ (row & 7)) << 3);
}

// ---------------------------------------------------------------------------
// K0: convert 4 weight matrices fp32->bf16. wall = [tw|pw|gw|Ww], 32768 each.
// theta weights pre-scaled by log2(e): scores land in exp2 domain.
// ---------------------------------------------------------------------------
__global__ __launch_bounds__(256) void k_cvtw(
    const float* __restrict__ tw, const float* __restrict__ pw,
    const float* __restrict__ gw, const float* __restrict__ Ww,
    u16* __restrict__ wall)
{
    int idx = (blockIdx.x * 256 + threadIdx.x) * 4;   // 0 .. 131071
    const float* s = (idx < 32768) ? tw
                   : (idx < 65536) ? pw
                   : (idx < 98304) ? gw : Ww;
    float sc = (idx < 32768) ? LOG2E : 1.0f;
    float4 v = *(const float4*)(s + (idx & 32767));
    us4 r = { f2bf(v.x * sc), f2bf(v.y * sc), f2bf(v.z * sc), f2bf(v.w * sc) };
    *(us4*)(wall + idx) = r;
}

// ---------------------------------------------------------------------------
// K1: MFMA projections, 512 threads. A = weights (global k-major frags),
// B = x^T tile in LDS (staged once, frags hoisted, reused 3x).
//  tht/pht: [b][n][c] bf16 k-major; gg: [b][c][n] bf16 (k-major in j).
//  theta bias scaled by log2e to match pre-scaled weights.
// ---------------------------------------------------------------------------
__global__ __launch_bounds__(512) void k_proj(
    const float* __restrict__ x, const u16* __restrict__ wall,
    const float* __restrict__ tb, const float* __restrict__ pb,
    const float* __restrict__ gbias,
    u16* __restrict__ tht, u16* __restrict__ pht, u16* __restrict__ gg)
{
    __shared__ u16 xs[64 * 264];    // x^T tile [n][c], pitch 264
    __shared__ u16 gbuf[128 * 68];  // g transpose bounce [o][n]
    const int tid = threadIdx.x;
    const int n0  = blockIdx.x * 64;
    const int b   = blockIdx.y;
    const int ln  = tid & 15, q = (tid >> 4) & 3, wid = tid >> 6;
    const int ow  = wid & 1, nw = wid >> 1;

    for (int p = 0; p < 8; ++p) {
        int id = p * 512 + tid;          // 4096 chunks: c(256) x n4(16)
        int c = id >> 4, n4 = (id & 15) * 4;
        float4 xv = *(const float4*)(x + ((size_t)b * CC + c) * NN + n0 + n4);
        xs[(n4 + 0) * 264 + c] = f2bf(xv.x);
        xs[(n4 + 1) * 264 + c] = f2bf(xv.y);
        xs[(n4 + 2) * 264 + c] = f2bf(xv.z);
        xs[(n4 + 3) * 264 + c] = f2bf(xv.w);
    }
    __syncthreads();

    short8 bfr[8];
    #pragma unroll
    for (int ks = 0; ks < 8; ++ks)
        bfr[ks] = *(const short8*)(&xs[(nw * 16 + ln) * 264 + ks * 32 + q * 8]);

    for (int pr = 0; pr < 3; ++pr) {
        const u16* wsrc = wall + pr * 32768;
        f32x4 acc[4];
        #pragma unroll
        for (int oo = 0; oo < 4; ++oo) acc[oo] = (f32x4){0.f, 0.f, 0.f, 0.f};
        for (int ks = 0; ks < 8; ++ks) {
            short8 a[4];
            #pragma unroll
            for (int oo = 0; oo < 4; ++oo)
                a[oo] = *(const short8*)(wsrc + (size_t)(ow*64 + oo*16 + ln) * 256 + ks*32 + q*8);
            #pragma unroll
            for (int oo = 0; oo < 4; ++oo)
                acc[oo] = MFMA16(a[oo], bfr[ks], acc[oo]);
        }
        const float* bias = (pr == 0) ? tb : (pr == 1 ? pb : gbias);
        const float bsc = (pr == 0) ? LOG2E : 1.0f;
        if (pr < 2) {
            u16* dst = (pr == 0) ? tht : pht;
            const int n = n0 + nw * 16 + ln;
            #pragma unroll
            for (int oo = 0; oo < 4; ++oo) {
                int o = ow * 64 + oo * 16 + q * 4;
                float4 bv = *(const float4*)(bias + o);
                f32x4 v = acc[oo];
                uint2 r = { pkbf(v.x + bv.x * bsc, v.y + bv.y * bsc),
                            pkbf(v.z + bv.z * bsc, v.w + bv.w * bsc) };
                *(uint2*)(dst + ((size_t)b * NN + n) * CHN + o) = r;
            }
        } else {
            const int nl = nw * 16 + ln;
            #pragma unroll
            for (int oo = 0; oo < 4; ++oo) {
                int o = ow * 64 + oo * 16 + q * 4;
                float4 bv = *(const float4*)(bias + o);
                f32x4 v = acc[oo];
                gbuf[(o + 0) * 68 + nl] = f2bf(v.x + bv.x);
                gbuf[(o + 1) * 68 + nl] = f2bf(v.y + bv.y);
                gbuf[(o + 2) * 68 + nl] = f2bf(v.z + bv.z);
                gbuf[(o + 3) * 68 + nl] = f2bf(v.w + bv.w);
            }
            __syncthreads();
            for (int p = 0; p < 4; ++p) {
                int id = p * 512 + tid;      // 2048 chunks: c(128) x n4(16)
                int c = id >> 4, n4 = (id & 15) * 4;
                us4 r = *(const us4*)(&gbuf[c * 68 + n4]);
                *(us4*)(gg + ((size_t)b * CHN + c) * NN + n0 + n4) = r;
            }
        }
    }
}

// ---------------------------------------------------------------------------
// K2: partial Z[b][j] += sum_{i in half} exp2(S2_ji), via fp32 atomicAdd.
// Block: j-tile 128 (theta frags hoisted to regs), i-half 2048 staged in LDS
// 128-chunks. Grid (32, 2, B) = 256 blocks, 512 threads, 64 KB LDS.
// No max-subtraction: |S| <= ~66*log2e < 127 (exp2 range), Z < ~1e28 (fp32 ok).
// ---------------------------------------------------------------------------
__global__ __launch_bounds__(512) void k_rowsum(
    const u16* __restrict__ tht, const u16* __restrict__ pht,
    float* __restrict__ Z)
{
    __shared__ u16 th_s[128 * 128];
    __shared__ u16 ph_s[128 * 128];
    __shared__ float zs[128][2];
    const int tid = threadIdx.x;
    const int j0  = blockIdx.x * 128;
    const int ih  = blockIdx.y;
    const int b   = blockIdx.z;
    const int ln  = tid & 15, q = (tid >> 4) & 3, wid = tid >> 6;
    const int jw  = wid & 3, iw = wid >> 2;

    { // stage theta j-tile once
        const u16* src = tht + ((size_t)b * NN + j0) * CHN;
        for (int p = 0; p < 4; ++p) {
            int id = p * 512 + tid;
            int row = id >> 4, u = id & 15;
            short8 v = *(const short8*)(src + row * 128 + u * 8);
            *(short8*)(&th_s[sw128(row, u)]) = v;
        }
    }
    __syncthreads();
    short8 ar[2][4];
    #pragma unroll
    for (int jj = 0; jj < 2; ++jj)
        #pragma unroll
        for (int ks = 0; ks < 4; ++ks)
            ar[jj][ks] = *(const short8*)(&th_s[sw128(jw*32 + jj*16 + ln, ks*4 + q)]);

    float zp[2][4];
    #pragma unroll
    for (int jj = 0; jj < 2; ++jj)
        #pragma unroll
        for (int r = 0; r < 4; ++r) zp[jj][r] = 0.f;

    const u16* phb = pht + ((size_t)b * NN + ih * 2048) * CHN;
    for (int is = 0; is < 16; ++is) {
        __syncthreads();   // ph_s frags consumed (and th hoist done, is=0)
        for (int p = 0; p < 4; ++p) {
            int id = p * 512 + tid;
            int row = id >> 4, u = id & 15;
            short8 v = *(const short8*)(phb + (size_t)(is * 128 + row) * CHN + u * 8);
            *(short8*)(&ph_s[sw128(row, u)]) = v;
        }
        __syncthreads();

        f32x4 s[2][4];
        #pragma unroll
        for (int jj = 0; jj < 2; ++jj)
            #pragma unroll
            for (int ii = 0; ii < 4; ++ii) s[jj][ii] = (f32x4){0.f, 0.f, 0.f, 0.f};
        for (int ks = 0; ks < 4; ++ks) {
            short8 bb[4];
            #pragma unroll
            for (int ii = 0; ii < 4; ++ii)
                bb[ii] = *(const short8*)(&ph_s[sw128(iw*64 + ii*16 + ln, ks*4 + q)]);
            #pragma unroll
            for (int jj = 0; jj < 2; ++jj)
                #pragma unroll
                for (int ii = 0; ii < 4; ++ii)
                    s[jj][ii] = MFMA16(ar[jj][ks], bb[ii], s[jj][ii]);
        }
        #pragma unroll
        for (int jj = 0; jj < 2; ++jj)
            #pragma unroll
            for (int ii = 0; ii < 4; ++ii) {
                f32x4 v = s[jj][ii];
                zp[jj][0] += EXP2F(v.x);
                zp[jj][1] += EXP2F(v.y);
                zp[jj][2] += EXP2F(v.z);
                zp[jj][3] += EXP2F(v.w);
            }
    }

    #pragma unroll
    for (int jj = 0; jj < 2; ++jj)
        #pragma unroll
        for (int r = 0; r < 4; ++r) {
            float v = zp[jj][r];
            v += __shfl_xor(v, 1);
            v += __shfl_xor(v, 2);
            v += __shfl_xor(v, 4);
            v += __shfl_xor(v, 8);
            if (ln == 0) zs[jw*32 + jj*16 + q*4 + r][iw] = v;
        }
    __syncthreads();
    if (tid < 128)
        atomicAdd(&Z[(size_t)b * NN + j0 + tid], zs[tid][0] + zs[tid][1]);
}

// ---------------------------------------------------------------------------
// K3: fused attention, 512 threads, i-tile 256 (phi frags REGISTER-resident),
// j-quarter 1024 (8 steps x 128, th/g staged in LDS per step).
//  phase1: S2 = th'_j.ph_i, C-init = -log2(Z_j)  ->  E = exp2(S2-L) bf16
//  phase2: innerT[i][c] += E[i][j] * g[c][j]
// LDS: th 32K + g 32K + E 64K = 128 KB; 8 waves = 2/SIMD. Grid (16,4,B)=256.
// ---------------------------------------------------------------------------
__global__ __launch_bounds__(512, 2) void k_attn(
    const u16* __restrict__ tht, const u16* __restrict__ pht,
    const u16* __restrict__ gg, const float* __restrict__ Z,
    u16* __restrict__ innerT)
{
    __shared__ u16 th_s[128 * 128];
    __shared__ u16 g_s [128 * 128];
    __shared__ u16 E_s [256 * 128];
    const int tid = threadIdx.x;
    const int i0  = blockIdx.x * 256;
    const int jq  = blockIdx.y;
    const int b   = blockIdx.z;
    const int ln  = tid & 15, q = (tid >> 4) & 3, wid = tid >> 6;
    const int h1  = wid & 1;    // phase1 j-half / phase2 c-half (of 64)
    const int h2  = wid >> 1;   // i-group (4 groups of 64)

    const u16*  thb = tht + (size_t)b * NN * CHN;
    const u16*  ggb = gg  + (size_t)b * CHN * NN;
    const float* Zb = Z   + (size_t)b * NN;

    { // stage phi i-tile into E_s, then hoist frags to registers
        const u16* src = pht + ((size_t)b * NN + i0) * CHN;
        for (int p = 0; p < 8; ++p) {
            int id = p * 512 + tid;
            int row = id >> 4, u = id & 15;
            short8 v = *(const short8*)(src + row * 128 + u * 8);
            *(short8*)(&E_s[sw128(row, u)]) = v;
        }
    }
    __syncthreads();
    short8 phr[4][4];
    #pragma unroll
    for (int ii = 0; ii < 4; ++ii)
        #pragma unroll
        for (int ks = 0; ks < 4; ++ks)
            phr[ii][ks] = *(const short8*)(&E_s[sw128(h2*64 + ii*16 + ln, ks*4 + q)]);

    f32x4 pacc[4][4];   // [cc][ii]
    #pragma unroll
    for (int cc = 0; cc < 4; ++cc)
        #pragma unroll
        for (int ii = 0; ii < 4; ++ii) pacc[cc][ii] = (f32x4){0.f, 0.f, 0.f, 0.f};

    for (int js = 0; js < 8; ++js) {
        const int j0 = jq * 1024 + js * 128;
        __syncthreads();   // E_s free (phi hoisted / prev phase2 done)
        for (int p = 0; p < 4; ++p) {
            int id = p * 512 + tid;
            int row = id >> 4, u = id & 15;
            short8 v = *(const short8*)(thb + (size_t)(j0 + row) * CHN + u * 8);
            *(short8*)(&th_s[sw128(row, u)]) = v;
        }
        for (int p = 0; p < 4; ++p) {
            int id = p * 512 + tid;
            int row = id >> 4, u = id & 15;
            short8 v = *(const short8*)(ggb + (size_t)row * NN + j0 + u * 8);
            *(short8*)(&g_s[sw128(row, u)]) = v;
        }
        __syncthreads();

        // ---- phase 1 (per jj to cap register pressure)
        #pragma unroll
        for (int jj = 0; jj < 4; ++jj) {
            const int jl = h1*64 + jj*16 + q*4;
            float4 Zv = *(const float4*)(Zb + j0 + jl);
            f32x4 cinit = { -LOG2F(Zv.x), -LOG2F(Zv.y), -LOG2F(Zv.z), -LOG2F(Zv.w) };
            f32x4 s0 = cinit, s1 = cinit, s2 = cinit, s3 = cinit;
            #pragma unroll
            for (int ks = 0; ks < 4; ++ks) {
                short8 a = *(const short8*)(&th_s[sw128(h1*64 + jj*16 + ln, ks*4 + q)]);
                s0 = MFMA16(a, phr[0][ks], s0);
                s1 = MFMA16(a, phr[1][ks], s1);
                s2 = MFMA16(a, phr[2][ks], s2);
                s3 = MFMA16(a, phr[3][ks], s3);
            }
            const int u = jl >> 3, off = jl & 7;
            f32x4 sv[4] = { s0, s1, s2, s3 };
            #pragma unroll
            for (int ii = 0; ii < 4; ++ii) {
                int ri = h2*64 + ii*16 + ln;
                f32x4 v = sv[ii];
                uint2 e = { pkbf(EXP2F(v.x), EXP2F(v.y)),
                            pkbf(EXP2F(v.z), EXP2F(v.w)) };
                *(uint2*)(&E_s[ri*128 + ((u ^ (ri & 7)) << 3) + off]) = e;
            }
        }
        __syncthreads();

        // ---- phase 2: innerT += g x E
        #pragma unroll
        for (int ks = 0; ks < 4; ++ks) {
            short8 be[4];
            #pragma unroll
            for (int ii = 0; ii < 4; ++ii)
                be[ii] = *(const short8*)(&E_s[sw128(h2*64 + ii*16 + ln, ks*4 + q)]);
            #pragma unroll
            for (int cc = 0; cc < 4; ++cc) {
                short8 ag = *(const short8*)(&g_s[sw128(h1*64 + cc*16 + ln, ks*4 + q)]);
                pacc[cc][0] = MFMA16(ag, be[0], pacc[cc][0]);
                pacc[cc][1] = MFMA16(ag, be[1], pacc[cc][1]);
                pacc[cc][2] = MFMA16(ag, be[2], pacc[cc][2]);
                pacc[cc][3] = MFMA16(ag, be[3], pacc[cc][3]);
            }
        }
    }

    // epilogue: D col=i (lane), rows = 4 consecutive c -> 8B stores into [i][c]
    u16* dst = innerT + ((size_t)jq * BB + b) * (size_t)NN * CHN;
    #pragma unroll
    for (int cc = 0; cc < 4; ++cc)
        #pragma unroll
        for (int ii = 0; ii < 4; ++ii) {
            int i = i0 + h2*64 + ii*16 + ln;
            int c = h1*64 + cc*16 + q*4;
            f32x4 v = pacc[cc][ii];
            uint2 r = { pkbf(v.x, v.y), pkbf(v.z, v.w) };
            *(uint2*)(dst + (size_t)i * CHN + c) = r;
        }
}

// ---------------------------------------------------------------------------
// K4: out[b][o][n] = Wb[o] + x[b][o][n] + sum_c Ww[o][c]*(sum_q innerT_q)[n][c]
// Pure-MFMA, quarter partials summed in the fp32 accumulator.
// ---------------------------------------------------------------------------
__global__ __launch_bounds__(512) void k_final(
    const u16* __restrict__ innerT, const float* __restrict__ x,
    const u16* __restrict__ Wwbf, const float* __restrict__ Wb,
    float* __restrict__ out)
{
    const int tid = threadIdx.x;
    const int n0  = blockIdx.x * 64;
    const int b   = blockIdx.y;
    const int ln  = tid & 15, q = (tid >> 4) & 3, wid = tid >> 6;

    f32x4 acc[4][2];
    #pragma unroll
    for (int nn = 0; nn < 4; ++nn)
        #pragma unroll
        for (int oo = 0; oo < 2; ++oo) acc[nn][oo] = (f32x4){0.f, 0.f, 0.f, 0.f};

    for (int jq = 0; jq < 4; ++jq) {
        const u16* src = innerT + ((size_t)jq * BB + b) * (size_t)NN * CHN;
        for (int ks = 0; ks < 4; ++ks) {
            short8 a[4], bw[2];
            #pragma unroll
            for (int nn = 0; nn < 4; ++nn)
                a[nn] = *(const short8*)(src + (size_t)(n0 + nn*16 + ln) * CHN + ks*32 + q*8);
            #pragma unroll
            for (int oo = 0; oo < 2; ++oo)
                bw[oo] = *(const short8*)(Wwbf + (size_t)(wid*32 + oo*16 + ln) * CHN + ks*32 + q*8);
            #pragma unroll
            for (int nn = 0; nn < 4; ++nn)
                #pragma unroll
                for (int oo = 0; oo < 2; ++oo)
                    acc[nn][oo] = MFMA16(a[nn], bw[oo], acc[nn][oo]);
        }
    }
    #pragma unroll
    for (int nn = 0; nn < 4; ++nn)
        #pragma unroll
        for (int oo = 0; oo < 2; ++oo) {
            int o = wid*32 + oo*16 + ln;
            int n = n0 + nn*16 + q*4;
            size_t idx = ((size_t)b * CC + o) * NN + n;
            float4 xv = *(const float4*)(x + idx);
            float wb = Wb[o];
            f32x4 v = acc[nn][oo];
            f32x4 r = { v.x + wb + xv.x, v.y + wb + xv.y,
                        v.z + wb + xv.z, v.w + wb + xv.w };
            *(f32x4*)(out + idx) = r;
        }
}

// ---------------------------------------------------------------------------
extern "C" void kernel_launch(void* const* d_in, const int* in_sizes, int n_in,
                              void* d_out, int out_size, void* d_ws, size_t ws_size,
                              hipStream_t stream)
{
    const float* x  = (const float*)d_in[0];
    const float* tw = (const float*)d_in[1];
    const float* tb = (const float*)d_in[2];
    const float* pw = (const float*)d_in[3];
    const float* pb = (const float*)d_in[4];
    const float* gw = (const float*)d_in[5];
    const float* gb = (const float*)d_in[6];
    const float* Ww = (const float*)d_in[7];
    const float* Wb = (const float*)d_in[8];
    float* out = (float*)d_out;

    // Workspace (~29 MB): tht|pht|gg (4MB ea bf16) | wall (256KB) |
    // Z (64KB fp32, memset to 0) | innerT 4 quarters x 4MB bf16.
    char* p = (char*)d_ws;
    const size_t proj_u16 = (size_t)BB * NN * CHN;   // 2,097,152
    u16*   tht    = (u16*)p;   p += proj_u16 * 2;
    u16*   pht    = (u16*)p;   p += proj_u16 * 2;
    u16*   gg     = (u16*)p;   p += proj_u16 * 2;
    u16*   wall   = (u16*)p;   p += (size_t)131072 * 2;
    float* Z      = (float*)p; p += (size_t)BB * NN * 4;
    u16*   innerT = (u16*)p;

    hipMemsetAsync(Z, 0, (size_t)BB * NN * sizeof(float), stream);
    k_cvtw  <<<128, 256, 0, stream>>>(tw, pw, gw, Ww, wall);
    k_proj  <<<dim3(64, BB), 512, 0, stream>>>(x, wall, tb, pb, gb, tht, pht, gg);
    k_rowsum<<<dim3(32, 2, BB), 512, 0, stream>>>(tht, pht, Z);
    k_attn  <<<dim3(16, 4, BB), 512, 0, stream>>>(tht, pht, gg, Z, innerT);
    k_final <<<dim3(64, BB), 512, 0, stream>>>(innerT, x, wall + 98304, Wb, out);
}